// Round 4
// baseline (629.498 us; speedup 1.0000x reference)
//
#include <hip/hip_runtime.h>

// GHM Dice loss, 3 passes:
//  k_reduce1: I = sum(p*t), sumP, sumT                        (reads p,t)
//  k_pass2:   histogram counts[10] + binsum[10] of 2*p*t, tot (reads p,t,lw)
//  k_final:   combine scalars -> loss
//
// Round-4 changes (theory: r3 was LATENCY-bound, not BW-bound — a zero-fetch
// L3-resident replay of k_reduce1 still took 155 us at VALUBusy 4%):
//  1. Fixed-trip contiguous chunks: each block owns an exact chunk; the K-deep
//     unrolled load loops have compile-time bounds -> 12-16 independent
//     global_load_dwordx4 in flight per thread (grid-stride + unroll couldn't
//     hoist loads past the per-copy bounds guards -> ~1 load in flight).
//  2. k_pass2 binning via per-thread LDS histogram with a DUMMY slot:
//     slot = inr ? b : 10 (one cndmask), then plain ds RMW — no atomics, no
//     10-way register select (that select was ~50 VALU/elem = 85 us/CU, above
//     the 64 us memory floor). Stride 23 words/thread: odd stride -> 2
//     lanes/bank baseline (free, m136).
//
// ws layout (floats): [0]=I [1]=sumP [2]=sumT [3]=tot [4..13]=counts [14..23]=binsum

constexpr int BINS = 10;
constexpr int K1 = 8;               // float4 per thread, k_reduce1
constexpr int K2 = 4;               // float4 per thread, k_pass2
constexpr int HSTR = 23;            // LDS words per thread: cnt 0..9, dummy 10, sum 12..21, dummy 22

__global__ __launch_bounds__(256) void k_reduce1(const float4* __restrict__ p,
                                                 const float4* __restrict__ t,
                                                 float* __restrict__ ws,
                                                 int n4, int n) {
    const int chunk = blockIdx.x * (256 * K1);
    const int base  = chunk + threadIdx.x;
    float sI = 0.f, sP = 0.f, sT = 0.f;

    if (chunk + 256 * K1 <= n4) {           // uniform: full chunk, no per-load guards
        float4 pv[K1], tv[K1];
#pragma unroll
        for (int k = 0; k < K1; ++k) pv[k] = p[base + k * 256];
#pragma unroll
        for (int k = 0; k < K1; ++k) tv[k] = t[base + k * 256];
#pragma unroll
        for (int k = 0; k < K1; ++k) {
            sI += pv[k].x * tv[k].x + pv[k].y * tv[k].y + pv[k].z * tv[k].z + pv[k].w * tv[k].w;
            sP += pv[k].x + pv[k].y + pv[k].z + pv[k].w;
            sT += tv[k].x + tv[k].y + tv[k].z + tv[k].w;
        }
    } else {                                // ragged last chunk
        for (int k = 0; k < K1; ++k) {
            int i = base + k * 256;
            if (i < n4) {
                float4 pv = p[i], tv = t[i];
                sI += pv.x * tv.x + pv.y * tv.y + pv.z * tv.z + pv.w * tv.w;
                sP += pv.x + pv.y + pv.z + pv.w;
                sT += tv.x + tv.y + tv.z + tv.w;
            }
        }
    }
    if (blockIdx.x == 0 && threadIdx.x == 0) {   // scalar tail (n % 4)
        const float* pf = (const float*)p;
        const float* tf = (const float*)t;
        for (int i = n4 * 4; i < n; ++i) { sI += pf[i] * tf[i]; sP += pf[i]; sT += tf[i]; }
    }
#pragma unroll
    for (int o = 32; o > 0; o >>= 1) {
        sI += __shfl_down(sI, o);
        sP += __shfl_down(sP, o);
        sT += __shfl_down(sT, o);
    }
    __shared__ float rI[4], rP[4], rT[4];
    int wave = threadIdx.x >> 6, lane = threadIdx.x & 63;
    if (lane == 0) { rI[wave] = sI; rP[wave] = sP; rT[wave] = sT; }
    __syncthreads();
    if (threadIdx.x == 0) {
        unsafeAtomicAdd(&ws[0], rI[0] + rI[1] + rI[2] + rI[3]);
        unsafeAtomicAdd(&ws[1], rP[0] + rP[1] + rP[2] + rP[3]);
        unsafeAtomicAdd(&ws[2], rT[0] + rT[1] + rT[2] + rT[3]);
    }
}

__global__ __launch_bounds__(256) void k_pass2(const float4* __restrict__ p,
                                               const float4* __restrict__ t,
                                               const float4* __restrict__ lw,
                                               float* __restrict__ ws,
                                               int n4, int n) {
    __shared__ float hist[256 * HSTR];
    for (int i = threadIdx.x; i < 256 * HSTR; i += 256) hist[i] = 0.f;
    __syncthreads();

    const float scale    = 2.f * ws[0] / (ws[1] + ws[2]);  // 2I/S
    const float edge_top = 1.0f + 1e-6f;
    float* __restrict__ mine = &hist[threadIdx.x * HSTR];

    const int chunk = blockIdx.x * (256 * K2);
    const int base  = chunk + threadIdx.x;
    float vcount = 0.f;

    auto process = [&](float pe, float te, float we) {
        bool valid = we > 0.f;
        vcount += valid ? 1.f : 0.f;
        float g = fabsf(scale * pe - te);
        bool inr = valid && (g < edge_top);
        int b = (int)(g * 10.f);             // g >= 0, trunc == floor
        b = b > (BINS - 1) ? (BINS - 1) : b;
        int slot = inr ? b : 10;             // invalid -> dummy slots (10 and 22)
        mine[slot]      += 1.f;              // cnt (ds RMW, per-thread region)
        mine[slot + 12] += 2.f * pe * te;    // sum
    };

    if (chunk + 256 * K2 <= n4) {            // uniform full chunk: 12 loads in flight
        float4 pv[K2], tv[K2], wv[K2];
#pragma unroll
        for (int k = 0; k < K2; ++k) pv[k] = p[base + k * 256];
#pragma unroll
        for (int k = 0; k < K2; ++k) tv[k] = t[base + k * 256];
#pragma unroll
        for (int k = 0; k < K2; ++k) wv[k] = lw[base + k * 256];
#pragma unroll
        for (int k = 0; k < K2; ++k) {
            process(pv[k].x, tv[k].x, wv[k].x);
            process(pv[k].y, tv[k].y, wv[k].y);
            process(pv[k].z, tv[k].z, wv[k].z);
            process(pv[k].w, tv[k].w, wv[k].w);
        }
    } else {
        for (int k = 0; k < K2; ++k) {
            int i = base + k * 256;
            if (i < n4) {
                float4 pv = p[i], tv = t[i], wv = lw[i];
                process(pv.x, tv.x, wv.x);
                process(pv.y, tv.y, wv.y);
                process(pv.z, tv.z, wv.z);
                process(pv.w, tv.w, wv.w);
            }
        }
    }
    if (blockIdx.x == 0 && threadIdx.x == 0) {   // scalar tail (n % 4)
        const float* pf = (const float*)p;
        const float* tf = (const float*)t;
        const float* wf = (const float*)lw;
        for (int i = n4 * 4; i < n; ++i) process(pf[i], tf[i], wf[i]);
    }

#pragma unroll
    for (int o = 32; o > 0; o >>= 1) vcount += __shfl_down(vcount, o);
    __shared__ float rV[4];
    int wave = threadIdx.x >> 6, lane = threadIdx.x & 63;
    if (lane == 0) rV[wave] = vcount;
    __syncthreads();
    if (threadIdx.x == 0) unsafeAtomicAdd(&ws[3], rV[0] + rV[1] + rV[2] + rV[3]);

    int tid = threadIdx.x;
    if (tid < 2 * BINS) {                    // cnt slots 0..9, sum slots 12..21
        int slot = (tid < BINS) ? tid : tid + 2;
        float v = 0.f;
        for (int i = 0; i < 256; ++i) v += hist[i * HSTR + slot];
        if (tid < BINS) unsafeAtomicAdd(&ws[4 + tid], v);
        else            unsafeAtomicAdd(&ws[14 + (tid - BINS)], v);
    }
}

__global__ void k_final(const float* __restrict__ ws, float* __restrict__ out) {
    if (threadIdx.x == 0 && blockIdx.x == 0) {
        float S   = ws[1] + ws[2];
        float tot = fmaxf(ws[3], 1.0f);
        int nne = 0;
        for (int b = 0; b < BINS; ++b) nne += (ws[4 + b] > 0.f) ? 1 : 0;
        float nn = fmaxf((float)nne, 1.0f);
        float wsum = 0.f;
        for (int b = 0; b < BINS; ++b) {
            float c = fmaxf(ws[4 + b], 1.0f);
            wsum += ws[14 + b] * (tot / c);   // binsum already carries 2*p*t
        }
        wsum /= nn;
        out[0] = 1.0f - wsum / S;
    }
}

extern "C" void kernel_launch(void* const* d_in, const int* in_sizes, int n_in,
                              void* d_out, int out_size, void* d_ws, size_t ws_size,
                              hipStream_t stream) {
    const float* p  = (const float*)d_in[0];
    const float* t  = (const float*)d_in[1];
    const float* lw = (const float*)d_in[2];
    float* ws  = (float*)d_ws;
    float* out = (float*)d_out;
    int n  = in_sizes[0];
    int n4 = n >> 2;

    hipMemsetAsync(d_ws, 0, (4 + 2 * BINS) * sizeof(float), stream);

    int blocks1 = (n4 + 256 * K1 - 1) / (256 * K1);   // 4096 at N=33.5M
    int blocks2 = (n4 + 256 * K2 - 1) / (256 * K2);   // 8192
    if (blocks1 < 1) blocks1 = 1;
    if (blocks2 < 1) blocks2 = 1;
    k_reduce1<<<blocks1, 256, 0, stream>>>((const float4*)p, (const float4*)t, ws, n4, n);
    k_pass2<<<blocks2, 256, 0, stream>>>((const float4*)p, (const float4*)t,
                                         (const float4*)lw, ws, n4, n);
    k_final<<<1, 64, 0, stream>>>(ws, out);
}

// Round 5
// 473.330 us; speedup vs baseline: 1.3299x; 1.3299x over previous
//
#include <hip/hip_runtime.h>

// GHM Dice loss, 4 dispatches, ZERO global atomics:
//  k_reduce1: per-block partials of {I=sum(p*t), sumP, sumT}  -> pws1   (reads p,t)
//  k_mid:     1-block reduce of pws1 -> ws[0]=2I/S, ws[1]=S
//  k_pass2:   per-block partials of {cnt[10], sm[10], vcount} -> pws2   (reads p,t,lw)
//  k_final:   1-block reduce of pws2 -> loss
//
// Round-5 theory: rounds 1-4 were floored by a device-wide SAME-ADDRESS global
// atomic serialization tail (~blocks x 50 cyc): r3 reduce1 took a fixed 155 us
// even on a zero-FETCH L3-resident replay (data residency irrelevant), and r4's
// 4096-block version took 186 us (tail scales with block count) despite 16
// loads in flight. Plain per-block partial stores + tiny second-stage kernels
// remove the tail entirely. Histogram stays in per-thread REGISTERS (r3
// structure, measured ~86 us incl. tail).
//
// ws float layout:
//   [0]=scale(2I/S) [1]=S            (written by k_mid)
//   [OFF1 + blk*4 + {0,1,2}]         pws1 per-block {I,P,T}
//   [OFF2 + blk*32 + {0..20}]        pws2 per-block {cnt0..9, sm0..9, vcount}
// Total ws: (OFF2 + 2048*32)*4 = 320 KB.

constexpr int BINS = 10;
constexpr int NB1  = 2048;
constexpr int NB2  = 2048;
constexpr int OFF1 = 64;
constexpr int OFF2 = 16384;

__global__ __launch_bounds__(256) void k_reduce1(const float4* __restrict__ p,
                                                 const float4* __restrict__ t,
                                                 float* __restrict__ ws,
                                                 int n4, int n) {
    int idx    = blockIdx.x * blockDim.x + threadIdx.x;
    int stride = gridDim.x * blockDim.x;
    float sI = 0.f, sP = 0.f, sT = 0.f;
#pragma unroll 4
    for (int i = idx; i < n4; i += stride) {
        float4 pv = p[i];
        float4 tv = t[i];
        sI += pv.x * tv.x + pv.y * tv.y + pv.z * tv.z + pv.w * tv.w;
        sP += pv.x + pv.y + pv.z + pv.w;
        sT += tv.x + tv.y + tv.z + tv.w;
    }
    if (idx == 0) {  // scalar tail (n % 4 != 0)
        const float* pf = (const float*)p;
        const float* tf = (const float*)t;
        for (int i = n4 * 4; i < n; ++i) { sI += pf[i] * tf[i]; sP += pf[i]; sT += tf[i]; }
    }
#pragma unroll
    for (int o = 32; o > 0; o >>= 1) {
        sI += __shfl_down(sI, o);
        sP += __shfl_down(sP, o);
        sT += __shfl_down(sT, o);
    }
    __shared__ float rI[4], rP[4], rT[4];
    int wave = threadIdx.x >> 6, lane = threadIdx.x & 63;
    if (lane == 0) { rI[wave] = sI; rP[wave] = sP; rT[wave] = sT; }
    __syncthreads();
    if (threadIdx.x == 0) {          // plain stores — NO atomics
        float* o = &ws[OFF1 + blockIdx.x * 4];
        o[0] = rI[0] + rI[1] + rI[2] + rI[3];
        o[1] = rP[0] + rP[1] + rP[2] + rP[3];
        o[2] = rT[0] + rT[1] + rT[2] + rT[3];
    }
}

__global__ __launch_bounds__(256) void k_mid(float* __restrict__ ws) {
    __shared__ float red[256];
    int tid = threadIdx.x;
    int q = tid & 3, idx = tid >> 2;
    float v = 0.f;
    if (q < 3)
        for (int b = idx; b < NB1; b += 64) v += ws[OFF1 + b * 4 + q];
    red[tid] = v;
    __syncthreads();
    if (tid < 3) {                   // lanes 0..2 of wave 0, lockstep-safe
        float s = 0.f;
        for (int i = 0; i < 64; ++i) s += red[i * 4 + tid];
        red[tid] = s;
    }
    __syncthreads();
    if (tid == 0) {
        float I = red[0];
        float S = red[1] + red[2];
        ws[0] = 2.f * I / S;
        ws[1] = S;
    }
}

__global__ __launch_bounds__(256) void k_pass2(const float4* __restrict__ p,
                                               const float4* __restrict__ t,
                                               const float4* __restrict__ lw,
                                               float* __restrict__ ws,
                                               int n4, int n) {
    const float scale    = ws[0];     // 2I/S
    const float edge_top = 1.0f + 1e-6f;

    // Per-thread register histogram — compile-time indexing only -> VGPRs.
    float cnt[BINS], sm[BINS];
#pragma unroll
    for (int b = 0; b < BINS; ++b) { cnt[b] = 0.f; sm[b] = 0.f; }
    float vcount = 0.f;

    int idx    = blockIdx.x * blockDim.x + threadIdx.x;
    int stride = gridDim.x * blockDim.x;

#pragma unroll 2
    for (int i = idx; i < n4; i += stride) {
        float4 pv = p[i], tv = t[i], wv = lw[i];
        float pj[4] = {pv.x, pv.y, pv.z, pv.w};
        float tj[4] = {tv.x, tv.y, tv.z, tv.w};
        float wj[4] = {wv.x, wv.y, wv.z, wv.w};
#pragma unroll
        for (int j = 0; j < 4; ++j) {
            bool valid = wj[j] > 0.f;
            vcount += valid ? 1.f : 0.f;
            float g = fabsf(scale * pj[j] - tj[j]);
            bool inr = valid && (g < edge_top);
            int b = (int)(g * 10.f);          // g >= 0, trunc == floor
            b = b > (BINS - 1) ? (BINS - 1) : b;
            float addc = inr ? 1.f : 0.f;
            float adds = inr ? 2.f * pj[j] * tj[j] : 0.f;
#pragma unroll
            for (int b0 = 0; b0 < BINS; ++b0) {
                bool m = (b == b0);
                cnt[b0] += m ? addc : 0.f;
                sm[b0]  += m ? adds : 0.f;
            }
        }
    }
    if (idx == 0) {  // scalar tail
        const float* pf = (const float*)p;
        const float* tf = (const float*)t;
        const float* wf = (const float*)lw;
        for (int i = n4 * 4; i < n; ++i) {
            bool valid = wf[i] > 0.f;
            vcount += valid ? 1.f : 0.f;
            float g = fabsf(scale * pf[i] - tf[i]);
            bool inr = valid && (g < edge_top);
            int b = (int)(g * 10.f);
            b = b > (BINS - 1) ? (BINS - 1) : b;
            float addc = inr ? 1.f : 0.f;
            float adds = inr ? 2.f * pf[i] * tf[i] : 0.f;
#pragma unroll
            for (int b0 = 0; b0 < BINS; ++b0) {
                bool m = (b == b0);
                cnt[b0] += m ? addc : 0.f;
                sm[b0]  += m ? adds : 0.f;
            }
        }
    }

    // Block reduction: LDS transpose (stride 21 odd -> free 2-lane/bank).
    __shared__ float red[256 * 21];
    float* mine = &red[threadIdx.x * 21];
#pragma unroll
    for (int b0 = 0; b0 < BINS; ++b0) { mine[b0] = cnt[b0]; mine[BINS + b0] = sm[b0]; }
    mine[2 * BINS] = vcount;
    __syncthreads();

    int tid = threadIdx.x;
    if (tid < 2 * BINS + 1) {
        float v = 0.f;
        for (int i = 0; i < 256; ++i) v += red[i * 21 + tid];
        ws[OFF2 + blockIdx.x * 32 + tid] = v;   // plain store — NO atomics
    }
}

__global__ __launch_bounds__(256) void k_final(const float* __restrict__ ws,
                                               float* __restrict__ out) {
    __shared__ float red[256];
    __shared__ float fin[32];
    int tid  = threadIdx.x;
    int slot = tid & 31;     // 0..20 used
    int grp  = tid >> 5;     // 8 groups
    float v = 0.f;
    if (slot < 2 * BINS + 1)
        for (int b = grp; b < NB2; b += 8) v += ws[OFF2 + b * 32 + slot];
    red[tid] = v;
    __syncthreads();
    if (tid < 32) {
        float s = 0.f;
#pragma unroll
        for (int g = 0; g < 8; ++g) s += red[g * 32 + tid];
        fin[tid] = s;
    }
    __syncthreads();
    if (tid == 0) {
        float S   = ws[1];
        float tot = fmaxf(fin[20], 1.0f);
        int nne = 0;
        for (int b = 0; b < BINS; ++b) nne += (fin[b] > 0.f) ? 1 : 0;
        float nn = fmaxf((float)nne, 1.0f);
        float wsum = 0.f;
        for (int b = 0; b < BINS; ++b) {
            float c = fmaxf(fin[b], 1.0f);
            wsum += fin[BINS + b] * (tot / c);   // fin[10+b] carries sum of 2*p*t
        }
        wsum /= nn;
        out[0] = 1.0f - wsum / S;
    }
}

extern "C" void kernel_launch(void* const* d_in, const int* in_sizes, int n_in,
                              void* d_out, int out_size, void* d_ws, size_t ws_size,
                              hipStream_t stream) {
    const float* p  = (const float*)d_in[0];
    const float* t  = (const float*)d_in[1];
    const float* lw = (const float*)d_in[2];
    float* ws  = (float*)d_ws;
    float* out = (float*)d_out;
    int n  = in_sizes[0];
    int n4 = n >> 2;

    k_reduce1<<<NB1, 256, 0, stream>>>((const float4*)p, (const float4*)t, ws, n4, n);
    k_mid<<<1, 256, 0, stream>>>(ws);
    k_pass2<<<NB2, 256, 0, stream>>>((const float4*)p, (const float4*)t,
                                     (const float4*)lw, ws, n4, n);
    k_final<<<1, 256, 0, stream>>>(ws, out);
}